// Round 3
// baseline (1886.368 us; speedup 1.0000x reference)
//
#include <hip/hip_runtime.h>
#include <hip/hip_bf16.h>
#include <stdint.h>

// ---------------- problem constants ----------------
#define B_    2
#define S_    4096
#define D_    2048
#define F_    8192
#define L_    2
#define FQ    (F_ / 4)         // 2048: F processed in quarters to cap workspace
#define NTOK  (B_ * S_)        // 8192 tokens
#define RCAP  (NTOK + 128)     // 8320 rows: 128-row zero gap between levels
#define EPS_  1e-6f

typedef __attribute__((ext_vector_type(8))) short s16x8;   // 8 bf16 in 4 VGPRs
typedef __attribute__((ext_vector_type(4))) float f32x4;   // 4 fp32 acc

typedef unsigned short u16;
typedef unsigned int   u32;

// ---------------- workspace layout (bytes) ----------------
#define OFF_CNT   ((size_t)0)          // int[32] padded counters
#define OFF_ZL    ((size_t)128)        // float[64] sharded z-loss accum
#define OFF_MAP   ((size_t)384)        // int[RCAP]
#define OFF_WROW  ((size_t)33664)      // float[RCAP]
#define OFF_WTOK  ((size_t)66944)      // float[NTOK]
#define OFF_XG    ((size_t)99712)      // bf16[RCAP][D_]  (34.1 MB)
#define OFF_HQ    ((size_t)34178432)   // bf16[RCAP][FQ]  (34.1 MB)
#define OFF_WA    ((size_t)68257152)   // bf16 L*FQ*D_ (16 MB): WgT quarter, then WdT quarter
#define OFF_WB    ((size_t)85034368)   // bf16 L*FQ*D_ (16 MB): WuT quarter
// end = 101,811,584 B

__device__ __forceinline__ u16 f2bf(float f) {
    u32 u = __builtin_bit_cast(u32, f);
    u += 0x7fff + ((u >> 16) & 1);      // RNE
    return (u16)(u >> 16);
}

// async global->LDS, 16B per lane. LDS dest wave-uniform base + lane*16.
__device__ __forceinline__ void gl16(const u16* g, u16* l) {
    __builtin_amdgcn_global_load_lds(
        (const __attribute__((address_space(1))) void*)g,
        (__attribute__((address_space(3))) void*)l, 16, 0, 0);
}

#define MF(acc, va, vb) acc = __builtin_amdgcn_mfma_f32_16x16x32_bf16(va, vb, acc, 0, 0, 0)

// ---------------- init ----------------
__global__ void k_init(int* counts, float* zacc) {
    if (threadIdx.x == 0) { counts[0] = 0; counts[16] = 0; }
    zacc[threadIdx.x & 63] = 0.f;
}

// ---------------- router + rmsnorm + gather ----------------
__global__ __launch_bounds__(256) void k_router(
    const float* __restrict__ hs, const float* __restrict__ rw,
    const float* __restrict__ nw, int* __restrict__ counts,
    float* __restrict__ zacc, int* __restrict__ tmap,
    float* __restrict__ wrow, float* __restrict__ wtok, u16* __restrict__ Xg)
{
    int t = blockIdx.x;
    int tid = threadIdx.x;
    const float* x = hs + (size_t)t * D_;
    float xs[8];
    float sxx = 0.f, s0 = 0.f, s1 = 0.f;
#pragma unroll
    for (int i = 0; i < 8; i++) {
        int d = tid + i * 256;
        float v = x[d];
        xs[i] = v;
        sxx += v * v;
        s0  += v * rw[d];
        s1  += v * rw[D_ + d];
    }
#pragma unroll
    for (int off = 32; off; off >>= 1) {
        sxx += __shfl_down(sxx, off, 64);
        s0  += __shfl_down(s0,  off, 64);
        s1  += __shfl_down(s1,  off, 64);
    }
    __shared__ float red[3][4];
    __shared__ float bcf[1];
    __shared__ int   bci[2];
    int wave = tid >> 6, lane = tid & 63;
    if (lane == 0) { red[0][wave] = sxx; red[1][wave] = s0; red[2][wave] = s1; }
    __syncthreads();
    if (tid == 0) {
        sxx = red[0][0] + red[0][1] + red[0][2] + red[0][3];
        s0  = red[1][0] + red[1][1] + red[1][2] + red[1][3];
        s1  = red[2][0] + red[2][1] + red[2][2] + red[2][3];
        float m  = fmaxf(s0, s1);
        float e0 = __expf(s0 - m), e1 = __expf(s1 - m);
        float Z  = e0 + e1;
        int   idx = (s1 > s0) ? 1 : 0;
        float p   = ((idx == 0) ? e0 : e1) / Z;
        float z   = m + __logf(Z);
        atomicAdd(&zacc[t & 63], z * z * (1.0f / NTOK));
        int pos = atomicAdd(&counts[idx << 4], 1);
        int row = (idx == 0) ? pos : (RCAP - 1 - pos);
        tmap[row] = t;
        wrow[row] = p;
        wtok[t]   = p;
        bcf[0] = rsqrtf(sxx * (1.0f / D_) + EPS_);
        bci[0] = idx; bci[1] = row;
    }
    __syncthreads();
    float inv = bcf[0];
    int idx = bci[0], row = bci[1];
    u16* xr = Xg + (size_t)row * D_;
    const float* w = nw + (size_t)idx * D_;
#pragma unroll
    for (int i = 0; i < 8; i++) {
        int d = tid + i * 256;
        xr[d] = f2bf(xs[i] * inv * w[d]);
    }
}

// ---------------- zero the 128-row gap ----------------
__global__ __launch_bounds__(256) void k_gap(const int* counts, int* tmap, u16* Xg) {
    int row = counts[0] + blockIdx.x;
    uint4* p = (uint4*)(Xg + (size_t)row * D_);
    p[threadIdx.x] = make_uint4(0u, 0u, 0u, 0u);
    if (threadIdx.x == 0) tmap[row] = -1;
}

// ---------------- out init: out = (1+w)*hs ----------------
__global__ __launch_bounds__(256) void k_outinit(
    const float* __restrict__ hs, const float* __restrict__ wtok,
    float* __restrict__ out)
{
    int t = blockIdx.x;
    float c = 1.f + wtok[t];
    const float4* ip = (const float4*)(hs + (size_t)t * D_);
    float4* op = (float4*)(out + (size_t)t * D_);
#pragma unroll
    for (int i = 0; i < 2; i++) {
        float4 v = ip[threadIdx.x + i * 256];
        v.x *= c; v.y *= c; v.z *= c; v.w *= c;
        op[threadIdx.x + i * 256] = v;
    }
}

// ---------------- transpose + cast ----------------
__global__ __launch_bounds__(256) void k_transpose(
    const float* __restrict__ in, u16* __restrict__ out,
    int R, int C, int r0, int c0, int RL, int CL)
{
    __shared__ float tile[32][33];
    int lc0 = blockIdx.x * 32;
    int lr0 = blockIdx.y * 32;
    const float* ip = in + (size_t)blockIdx.z * (size_t)R * (size_t)C;
    u16* op = out + (size_t)blockIdx.z * (size_t)CL * (size_t)RL;
    int tx = threadIdx.x & 31, ty = threadIdx.x >> 5;
#pragma unroll
    for (int i = 0; i < 4; i++)
        tile[ty + i * 8][tx] = ip[(size_t)(r0 + lr0 + ty + i * 8) * C + (c0 + lc0 + tx)];
    __syncthreads();
#pragma unroll
    for (int i = 0; i < 4; i++)
        op[(size_t)(lc0 + ty + i * 8) * RL + lr0 + tx] = f2bf(tile[tx][ty + i * 8]);
}

// ---------------- GEMM1 (dual, pipelined): Hq = silu(Xg@WgTq^T)*(Xg@WuTq^T) ----------------
// grid (FQ/256=8, RCAP/128=65), 512 thr = 8 waves (2M x 4N), per-wave 64x64 of G AND U.
// BK=32, 3-buffer LDS ring (3 x 40KB = 120KB): tile t in buf t%3, stage t+2 during t.
// Counted vmcnt(5) once per tile (never 0 in main loop) + raw s_barrier (no drain).
// LDS swizzle: slot ^= row&3 within 64B rows, applied on gl16 SOURCE and ds_read (rule #21).
__global__ __launch_bounds__(512, 2) void k_gemm1(
    const u16* __restrict__ Xg, const u16* __restrict__ WgT,
    const u16* __restrict__ WuT, const int* __restrict__ counts,
    u16* __restrict__ Hq)
{
    int nt = blockIdx.x, mt = blockIdx.y;
    int count0 = counts[0];
    int level = (mt * 128 < count0) ? 0 : 1;
    const u16* Bg = WgT + (size_t)level * FQ * D_;
    const u16* Bu = WuT + (size_t)level * FQ * D_;

    // ring buf (u16): A [0,4096) 128x32, G [4096,12288) 256x32, U [12288,20480) 256x32
    __shared__ __align__(16) u16 lds[3 * 20480];   // 120 KiB

    int tid = threadIdx.x, lane = tid & 63, wave = tid >> 6;
    int wm = wave >> 2, wn = wave & 3;
    int quad = lane >> 4, ln = lane & 15;

    // staging: thread tid covers (row = tid>>2, 16B slot = tid&3) of each 128-row region
    int srow = tid >> 2;
    int sswz = ((tid & 3) ^ (srow & 3)) * 8;       // swizzled source slot (u16 units)
    const u16* gA  = Xg + (size_t)(mt * 128 + srow) * D_ + sswz;
    const u16* gG0 = Bg + (size_t)(nt * 256 + srow) * D_ + sswz;
    const u16* gG1 = gG0 + (size_t)128 * D_;
    const u16* gU0 = Bu + (size_t)(nt * 256 + srow) * D_ + sswz;
    const u16* gU1 = gU0 + (size_t)128 * D_;

    u16* wd = lds + wave * 512;    // wave-uniform dest offset inside each 8KB region

    f32x4 accG[4][4] = {}, accU[4][4] = {};

    // prologue: stage tiles 0,1 (5 loads each)
#pragma unroll
    for (int p = 0; p < 2; ++p) {
        u16* b = wd + p * 20480;
        gl16(gA  + p * 32, b);
        gl16(gG0 + p * 32, b + 4096);
        gl16(gG1 + p * 32, b + 8192);
        gl16(gU0 + p * 32, b + 12288);
        gl16(gU1 + p * 32, b + 16384);
    }
    asm volatile("s_waitcnt vmcnt(5)" ::: "memory");   // tile 0 landed; tile 1 in flight
    asm volatile("s_barrier" ::: "memory");

    int fswz = (quad ^ (ln & 3)) * 8;
    int aoff = (wm * 64 + ln) * 32 + fswz;
    int boff = (wn * 64 + ln) * 32 + fswz;

    int cur = 0;
    for (int t = 0; t < 64; ++t) {
        const u16* As = lds + cur * 20480;
        const u16* Gs = As + 4096;
        const u16* Us = As + 12288;
        int stg = cur + 2; if (stg >= 3) stg -= 3;
        u16* sb = lds + stg * 20480 + wave * 512;
        int koff = (t + 2) * 32;
        bool do_stage = (t + 2) < 64;              // uniform branch

        // ---- phase A: nj 0,1 ----
        s16x8 a[4], bg[2], bu[2];
#pragma unroll
        for (int i = 0; i < 4; ++i) a[i] = *(const s16x8*)(As + i * 512 + aoff);
#pragma unroll
        for (int j = 0; j < 2; ++j) {
            bg[j] = *(const s16x8*)(Gs + j * 512 + boff);
            bu[j] = *(const s16x8*)(Us + j * 512 + boff);
        }
        if (do_stage) {
            gl16(gA  + koff, sb);
            gl16(gG0 + koff, sb + 4096);
            gl16(gG1 + koff, sb + 8192);
        }
        __builtin_amdgcn_s_setprio(1);
#pragma unroll
        for (int mi = 0; mi < 4; ++mi)
#pragma unroll
            for (int j = 0; j < 2; ++j) {
                MF(accG[mi][j], a[mi], bg[j]);
                MF(accU[mi][j], a[mi], bu[j]);
            }
        __builtin_amdgcn_s_setprio(0);
        asm volatile("s_barrier" ::: "memory");

        // ---- phase B: nj 2,3 ----
#pragma unroll
        for (int j = 0; j < 2; ++j) {
            bg[j] = *(const s16x8*)(Gs + (2 + j) * 512 + boff);
            bu[j] = *(const s16x8*)(Us + (2 + j) * 512 + boff);
        }
        if (do_stage) {
            gl16(gU0 + koff, sb + 12288);
            gl16(gU1 + koff, sb + 16384);
        }
        __builtin_amdgcn_s_setprio(1);
#pragma unroll
        for (int mi = 0; mi < 4; ++mi)
#pragma unroll
            for (int j = 0; j < 2; ++j) {
                MF(accG[mi][2 + j], a[mi], bg[j]);
                MF(accU[mi][2 + j], a[mi], bu[j]);
            }
        __builtin_amdgcn_s_setprio(0);
        // ledger: outstanding = t+1's 5 + t+2's 5 -> wait to 5 => t+1 fully landed
        if (t < 62)       { asm volatile("s_waitcnt vmcnt(5)" ::: "memory"); }
        else if (t == 62) { asm volatile("s_waitcnt vmcnt(0)" ::: "memory"); }
        asm volatile("s_barrier" ::: "memory");
        cur = (cur == 2) ? 0 : cur + 1;
    }

    int rowbase = mt * 128 + wm * 64;
    int colbase = nt * 256 + wn * 64;
#pragma unroll
    for (int mi = 0; mi < 4; ++mi)
#pragma unroll
        for (int nj = 0; nj < 4; ++nj)
#pragma unroll
            for (int r = 0; r < 4; ++r) {
                float g = accG[mi][nj][r], u = accU[mi][nj][r];
                float h = g / (1.f + __expf(-g)) * u;   // silu(g)*u
                int row = rowbase + mi * 16 + quad * 4 + r;
                int col = colbase + nj * 16 + ln;
                Hq[(size_t)row * FQ + col] = f2bf(h);
            }
}

// ---------------- GEMM2 (pipelined): out[tok] += w * (Hq @ WdTq^T) ----------------
// grid (D_/256=8, 65), 512 thr = 8 waves (2M x 4N), per-wave 64x64.
// BK=32, 4-buffer ring (4 x 24KB = 96KB): stage t+3 during t, vmcnt(6).
__global__ __launch_bounds__(512, 2) void k_gemm2(
    const u16* __restrict__ Hq, const u16* __restrict__ WdT,
    const int* __restrict__ counts, const int* __restrict__ tmap,
    const float* __restrict__ wrow, float* __restrict__ out)
{
    int nt = blockIdx.x, mt = blockIdx.y;
    int count0 = counts[0];
    int level = (mt * 128 < count0) ? 0 : 1;
    const u16* Bd = WdT + (size_t)level * D_ * FQ;

    // ring buf (u16): A [0,4096) 128x32, B [4096,12288) 256x32
    __shared__ __align__(16) u16 lds[4 * 12288];   // 96 KiB
    __shared__ int   stok[128];
    __shared__ float sw[128];

    int tid = threadIdx.x, lane = tid & 63, wave = tid >> 6;
    int wm = wave >> 2, wn = wave & 3;
    int quad = lane >> 4, ln = lane & 15;

    if (tid < 128) { stok[tid] = tmap[mt * 128 + tid]; sw[tid] = wrow[mt * 128 + tid]; }

    int srow = tid >> 2;
    int sswz = ((tid & 3) ^ (srow & 3)) * 8;
    const u16* gA  = Hq + (size_t)(mt * 128 + srow) * FQ + sswz;
    const u16* gB0 = Bd + (size_t)(nt * 256 + srow) * FQ + sswz;
    const u16* gB1 = gB0 + (size_t)128 * FQ;

    u16* wd = lds + wave * 512;

    f32x4 acc[4][4] = {};

    // prologue: stage tiles 0,1,2 (3 loads each)
#pragma unroll
    for (int p = 0; p < 3; ++p) {
        u16* b = wd + p * 12288;
        gl16(gA  + p * 32, b);
        gl16(gB0 + p * 32, b + 4096);
        gl16(gB1 + p * 32, b + 8192);
    }
    asm volatile("s_waitcnt vmcnt(6)" ::: "memory");   // tile 0 landed
    asm volatile("s_barrier" ::: "memory");

    int fswz = (quad ^ (ln & 3)) * 8;
    int aoff = (wm * 64 + ln) * 32 + fswz;
    int boff = (wn * 64 + ln) * 32 + fswz;

    int cur = 0;
    for (int t = 0; t < 64; ++t) {
        const u16* As = lds + cur * 12288;
        const u16* Bs = As + 4096;
        int stg = cur + 3; if (stg >= 4) stg -= 4;
        u16* sb = lds + stg * 12288 + wave * 512;
        int koff = (t + 3) * 32;

        s16x8 a[4], b[4];
#pragma unroll
        for (int i = 0; i < 4; ++i) {
            a[i] = *(const s16x8*)(As + i * 512 + aoff);
            b[i] = *(const s16x8*)(Bs + i * 512 + boff);
        }
        if (t + 3 < 64) {
            gl16(gA  + koff, sb);
            gl16(gB0 + koff, sb + 4096);
            gl16(gB1 + koff, sb + 8192);
        }
        __builtin_amdgcn_s_setprio(1);
#pragma unroll
        for (int mi = 0; mi < 4; ++mi)
#pragma unroll
            for (int nj = 0; nj < 4; ++nj)
                MF(acc[mi][nj], a[mi], b[nj]);
        __builtin_amdgcn_s_setprio(0);
        // ledger: outstanding = t+1(3)+t+2(3)+t+3(3) -> wait to 6 => t+1 landed
        if (t < 61)       { asm volatile("s_waitcnt vmcnt(6)" ::: "memory"); }
        else if (t == 61) { asm volatile("s_waitcnt vmcnt(3)" ::: "memory"); }
        else if (t == 62) { asm volatile("s_waitcnt vmcnt(0)" ::: "memory"); }
        asm volatile("s_barrier" ::: "memory");
        cur = (cur == 3) ? 0 : cur + 1;
    }

    int colbase = nt * 256 + wn * 64;
#pragma unroll
    for (int mi = 0; mi < 4; ++mi)
#pragma unroll
        for (int nj = 0; nj < 4; ++nj)
#pragma unroll
            for (int r = 0; r < 4; ++r) {
                int rl = wm * 64 + mi * 16 + quad * 4 + r;
                int tok = stok[rl];
                if (tok < 0) continue;
                int col = colbase + nj * 16 + ln;
                out[(size_t)tok * D_ + col] += sw[rl] * acc[mi][nj][r];
            }
}

// ---------------- z-loss write ----------------
__global__ void k_zout(const float* zacc, float* out) {
    float s = 0.f;
#pragma unroll
    for (int i = 0; i < 64; i++) s += zacc[i];
    out[(size_t)NTOK * D_] = s;
}

extern "C" void kernel_launch(void* const* d_in, const int* in_sizes, int n_in,
                              void* d_out, int out_size, void* d_ws, size_t ws_size,
                              hipStream_t stream) {
    const float* hs = (const float*)d_in[0];
    const float* rw = (const float*)d_in[1];
    const float* Wg = (const float*)d_in[2];
    const float* Wu = (const float*)d_in[3];
    const float* Wd = (const float*)d_in[4];
    const float* nw = (const float*)d_in[5];
    float* out = (float*)d_out;

    char* ws = (char*)d_ws;
    int*   counts = (int*)(ws + OFF_CNT);
    float* zacc   = (float*)(ws + OFF_ZL);
    int*   tmap   = (int*)(ws + OFF_MAP);
    float* wrow   = (float*)(ws + OFF_WROW);
    float* wtok   = (float*)(ws + OFF_WTOK);
    u16*   Xg     = (u16*)(ws + OFF_XG);
    u16*   Hq     = (u16*)(ws + OFF_HQ);
    u16*   WA     = (u16*)(ws + OFF_WA);   // WgT quarter, then WdT quarter
    u16*   WB     = (u16*)(ws + OFF_WB);   // WuT quarter

    k_init<<<1, 64, 0, stream>>>(counts, zacc);
    k_router<<<NTOK, 256, 0, stream>>>(hs, rw, nw, counts, zacc, tmap, wrow, wtok, Xg);
    k_gap<<<128, 256, 0, stream>>>(counts, tmap, Xg);
    k_outinit<<<NTOK, 256, 0, stream>>>(hs, wtok, out);

    for (int q = 0; q < 4; q++) {
        // Wg, Wu are [L][D][F]: transpose col-range [q*FQ, +FQ) -> [L][FQ][D]
        k_transpose<<<dim3(FQ / 32, D_ / 32, L_), 256, 0, stream>>>(Wg, WA, D_, F_, 0, q * FQ, D_, FQ);
        k_transpose<<<dim3(FQ / 32, D_ / 32, L_), 256, 0, stream>>>(Wu, WB, D_, F_, 0, q * FQ, D_, FQ);
        k_gemm1<<<dim3(FQ / 256, RCAP / 128), 512, 0, stream>>>(Xg, WA, WB, counts, Hq);
        // Wd is [L][F][D]: transpose row-range [q*FQ, +FQ) -> [L][D][FQ]  (reuses WA)
        k_transpose<<<dim3(D_ / 32, FQ / 32, L_), 256, 0, stream>>>(Wd, WA, F_, D_, q * FQ, 0, FQ, D_);
        k_gemm2<<<dim3(D_ / 256, RCAP / 128), 512, 0, stream>>>(Hq, WA, counts, tmap, wrow, out);
    }
    k_zout<<<1, 1, 0, stream>>>(zacc, out);
}

// Round 6
// 1560.664 us; speedup vs baseline: 1.2087x; 1.2087x over previous
//
#include <hip/hip_runtime.h>
#include <hip/hip_bf16.h>
#include <stdint.h>

// ---------------- problem constants ----------------
#define B_    2
#define S_    4096
#define D_    2048
#define F_    8192
#define L_    2
#define FQ    (F_ / 4)         // 2048: F processed in quarters to cap workspace
#define NTOK  (B_ * S_)        // 8192 tokens
#define RCAP  (NTOK + 128)     // 8320 rows: 128-row zero gap between levels
#define EPS_  1e-6f

typedef __attribute__((ext_vector_type(8))) short s16x8;   // 8 bf16 in 4 VGPRs
typedef __attribute__((ext_vector_type(4))) float f32x4;   // 4 fp32 acc

typedef unsigned short u16;
typedef unsigned int   u32;

// ---------------- workspace layout (bytes) ----------------
#define OFF_CNT   ((size_t)0)          // int[32] padded counters
#define OFF_ZL    ((size_t)128)        // float[64] sharded z-loss accum
#define OFF_MAP   ((size_t)384)        // int[RCAP]
#define OFF_WROW  ((size_t)33664)      // float[RCAP]
#define OFF_WTOK  ((size_t)66944)      // float[NTOK]
#define OFF_XG    ((size_t)99712)      // bf16[RCAP][D_]  (34.1 MB)
#define OFF_HQ    ((size_t)34178432)   // bf16[RCAP][FQ]  (34.1 MB)
#define OFF_WA    ((size_t)68257152)   // bf16 L*FQ*D_ (16 MB): WgT quarter, then WdT quarter
#define OFF_WB    ((size_t)85034368)   // bf16 L*FQ*D_ (16 MB): WuT quarter
// end = 101,811,584 B

__device__ __forceinline__ u16 f2bf(float f) {
    u32 u = __builtin_bit_cast(u32, f);
    u += 0x7fff + ((u >> 16) & 1);      // RNE
    return (u16)(u >> 16);
}

// async global->LDS, 16B per lane. LDS dest wave-uniform base + lane*16.
__device__ __forceinline__ void gl16(const u16* g, u16* l) {
    __builtin_amdgcn_global_load_lds(
        (const __attribute__((address_space(1))) void*)g,
        (__attribute__((address_space(3))) void*)l, 16, 0, 0);
}

#define MF(acc, va, vb) acc = __builtin_amdgcn_mfma_f32_16x16x32_bf16(va, vb, acc, 0, 0, 0)

// ---------------- init ----------------
__global__ void k_init(int* counts, float* zacc) {
    if (threadIdx.x == 0) { counts[0] = 0; counts[16] = 0; }
    zacc[threadIdx.x & 63] = 0.f;
}

// ---------------- router + rmsnorm + gather ----------------
__global__ __launch_bounds__(256) void k_router(
    const float* __restrict__ hs, const float* __restrict__ rw,
    const float* __restrict__ nw, int* __restrict__ counts,
    float* __restrict__ zacc, int* __restrict__ tmap,
    float* __restrict__ wrow, float* __restrict__ wtok, u16* __restrict__ Xg)
{
    int t = blockIdx.x;
    int tid = threadIdx.x;
    const float* x = hs + (size_t)t * D_;
    float xs[8];
    float sxx = 0.f, s0 = 0.f, s1 = 0.f;
#pragma unroll
    for (int i = 0; i < 8; i++) {
        int d = tid + i * 256;
        float v = x[d];
        xs[i] = v;
        sxx += v * v;
        s0  += v * rw[d];
        s1  += v * rw[D_ + d];
    }
#pragma unroll
    for (int off = 32; off; off >>= 1) {
        sxx += __shfl_down(sxx, off, 64);
        s0  += __shfl_down(s0,  off, 64);
        s1  += __shfl_down(s1,  off, 64);
    }
    __shared__ float red[3][4];
    __shared__ float bcf[1];
    __shared__ int   bci[2];
    int wave = tid >> 6, lane = tid & 63;
    if (lane == 0) { red[0][wave] = sxx; red[1][wave] = s0; red[2][wave] = s1; }
    __syncthreads();
    if (tid == 0) {
        sxx = red[0][0] + red[0][1] + red[0][2] + red[0][3];
        s0  = red[1][0] + red[1][1] + red[1][2] + red[1][3];
        s1  = red[2][0] + red[2][1] + red[2][2] + red[2][3];
        float m  = fmaxf(s0, s1);
        float e0 = __expf(s0 - m), e1 = __expf(s1 - m);
        float Z  = e0 + e1;
        int   idx = (s1 > s0) ? 1 : 0;
        float p   = ((idx == 0) ? e0 : e1) / Z;
        float z   = m + __logf(Z);
        atomicAdd(&zacc[t & 63], z * z * (1.0f / NTOK));
        int pos = atomicAdd(&counts[idx << 4], 1);
        int row = (idx == 0) ? pos : (RCAP - 1 - pos);
        tmap[row] = t;
        wrow[row] = p;
        wtok[t]   = p;
        bcf[0] = rsqrtf(sxx * (1.0f / D_) + EPS_);
        bci[0] = idx; bci[1] = row;
    }
    __syncthreads();
    float inv = bcf[0];
    int idx = bci[0], row = bci[1];
    u16* xr = Xg + (size_t)row * D_;
    const float* w = nw + (size_t)idx * D_;
#pragma unroll
    for (int i = 0; i < 8; i++) {
        int d = tid + i * 256;
        xr[d] = f2bf(xs[i] * inv * w[d]);
    }
}

// ---------------- zero the 128-row gap ----------------
__global__ __launch_bounds__(256) void k_gap(const int* counts, int* tmap, u16* Xg) {
    int row = counts[0] + blockIdx.x;
    uint4* p = (uint4*)(Xg + (size_t)row * D_);
    p[threadIdx.x] = make_uint4(0u, 0u, 0u, 0u);
    if (threadIdx.x == 0) tmap[row] = -1;
}

// ---------------- out init: out = (1+w)*hs ----------------
__global__ __launch_bounds__(256) void k_outinit(
    const float* __restrict__ hs, const float* __restrict__ wtok,
    float* __restrict__ out)
{
    int t = blockIdx.x;
    float c = 1.f + wtok[t];
    const float4* ip = (const float4*)(hs + (size_t)t * D_);
    float4* op = (float4*)(out + (size_t)t * D_);
#pragma unroll
    for (int i = 0; i < 2; i++) {
        float4 v = ip[threadIdx.x + i * 256];
        v.x *= c; v.y *= c; v.z *= c; v.w *= c;
        op[threadIdx.x + i * 256] = v;
    }
}

// ---------------- fused Wg/Wu transpose: fp32 [L][D][F] col-range q*FQ..+FQ -> bf16 [L][FQ][D] ----------------
// z: bit0 = matrix (0=Wg->WA, 1=Wu->WB), bit1 = level
__global__ __launch_bounds__(256) void k_transposeGU(
    const float* __restrict__ Wg, const float* __restrict__ Wu,
    u16* __restrict__ WA, u16* __restrict__ WB, int c0)
{
    __shared__ float tile[32][33];
    int z = blockIdx.z;
    int m = z & 1, lvl = z >> 1;
    const float* ip = (m ? Wu : Wg) + (size_t)lvl * D_ * F_;
    u16* op = (m ? WB : WA) + (size_t)lvl * FQ * D_;
    int lc0 = blockIdx.x * 32;
    int lr0 = blockIdx.y * 32;
    int tx = threadIdx.x & 31, ty = threadIdx.x >> 5;
#pragma unroll
    for (int i = 0; i < 4; i++)
        tile[ty + i * 8][tx] = ip[(size_t)(lr0 + ty + i * 8) * F_ + (c0 + lc0 + tx)];
    __syncthreads();
#pragma unroll
    for (int i = 0; i < 4; i++)
        op[(size_t)(lc0 + ty + i * 8) * D_ + lr0 + tx] = f2bf(tile[tx][ty + i * 8]);
}

// ---------------- generic transpose (for Wd) ----------------
__global__ __launch_bounds__(256) void k_transpose(
    const float* __restrict__ in, u16* __restrict__ out,
    int R, int C, int r0, int c0, int RL, int CL)
{
    __shared__ float tile[32][33];
    int lc0 = blockIdx.x * 32;
    int lr0 = blockIdx.y * 32;
    const float* ip = in + (size_t)blockIdx.z * (size_t)R * (size_t)C;
    u16* op = out + (size_t)blockIdx.z * (size_t)CL * (size_t)RL;
    int tx = threadIdx.x & 31, ty = threadIdx.x >> 5;
#pragma unroll
    for (int i = 0; i < 4; i++)
        tile[ty + i * 8][tx] = ip[(size_t)(r0 + lr0 + ty + i * 8) * C + (c0 + lc0 + tx)];
    __syncthreads();
#pragma unroll
    for (int i = 0; i < 4; i++)
        op[(size_t)(lc0 + ty + i * 8) * RL + lr0 + tx] = f2bf(tile[tx][ty + i * 8]);
}

// ---------------- GEMM1 (dual): Hq = silu(Xg@WgTq^T) * (Xg@WuTq^T), bf16 ----------------
// grid (FQ/64=32, RCAP/128=65), 256 thr = 4 waves (2x2), per-wave 64x32 of G AND U.
// BK=64: 128B LDS rows -> slot^=(row&7) swizzle is conflict-free (bank = slot only);
// halves barrier count vs BK=32. Swizzle on gl16 SOURCE + ds_read (both-sides, rule #21).
// LDS padded to 44KB to cap at 3 blocks/CU (grid 2080 / 768 slots = 2.71 rounds, eff 0.90;
// 4 blocks/CU would quantize to 2080/1024 = 2.03 -> 3 rounds, eff 0.68).
__global__ __launch_bounds__(256, 3) void k_gemm1(
    const u16* __restrict__ Xg, const u16* __restrict__ WgT,
    const u16* __restrict__ WuT, const int* __restrict__ counts,
    u16* __restrict__ Hq)
{
    int nt = blockIdx.x, mt = blockIdx.y;
    int count0 = counts[0];
    int level = (mt * 128 < count0) ? 0 : 1;
    const u16* Bg = WgT + (size_t)level * FQ * D_;
    const u16* Bu = WuT + (size_t)level * FQ * D_;

    __shared__ __align__(16) u16 As[8192 + 6144];   // 128x64 + 12KB occupancy pad
    __shared__ __align__(16) u16 Gs[4096], Us[4096]; // 64x64 each  -> total 44KB

    int tid = threadIdx.x, lane = tid & 63, wave = tid >> 6;
    int wm = wave >> 1, wn = wave & 1;
    int quad = lane >> 4, ln = lane & 15;
    int swz = ln & 7;

    f32x4 accG[4][2] = {}, accU[4][2] = {};

    // staging: thread covers (row = tid>>3, 16B slot = tid&7) of 32-row stripes
    int srow = tid >> 3;
    int sswz = ((tid & 7) ^ (srow & 7)) * 8;      // pre-swizzled source slot (u16)
    const u16* gA = Xg + (size_t)(mt * 128 + srow) * D_ + sswz;
    const u16* gG = Bg + (size_t)(nt * 64 + srow) * D_ + sswz;
    const u16* gU = Bu + (size_t)(nt * 64 + srow) * D_ + sswz;
    u16* dA = As + wave * 512;                     // HW adds lane*16B
    u16* dG = Gs + wave * 512;
    u16* dU = Us + wave * 512;

    for (int k0 = 0; k0 < D_; k0 += 64) {
        __syncthreads();   // previous step's fragment reads complete
        gl16(gA + k0, dA);
        gl16(gA + (size_t)32 * D_ + k0, dA + 2048);
        gl16(gA + (size_t)64 * D_ + k0, dA + 4096);
        gl16(gA + (size_t)96 * D_ + k0, dA + 6144);
        gl16(gG + k0, dG);
        gl16(gG + (size_t)32 * D_ + k0, dG + 2048);
        gl16(gU + k0, dU);
        gl16(gU + (size_t)32 * D_ + k0, dU + 2048);
        __syncthreads();   // compiler drains vmcnt(0) -> LDS visible
#pragma unroll
        for (int h = 0; h < 2; ++h) {
            int ks = ((h * 4 + quad) ^ swz) * 8;
            s16x8 a[4], bg[2], bu[2];
#pragma unroll
            for (int i = 0; i < 4; ++i)
                a[i] = *(const s16x8*)(As + (wm * 64 + i * 16 + ln) * 64 + ks);
#pragma unroll
            for (int j = 0; j < 2; ++j) {
                bg[j] = *(const s16x8*)(Gs + (wn * 32 + j * 16 + ln) * 64 + ks);
                bu[j] = *(const s16x8*)(Us + (wn * 32 + j * 16 + ln) * 64 + ks);
            }
#pragma unroll
            for (int mi = 0; mi < 4; ++mi)
#pragma unroll
                for (int j = 0; j < 2; ++j) {
                    MF(accG[mi][j], a[mi], bg[j]);
                    MF(accU[mi][j], a[mi], bu[j]);
                }
        }
    }

    int rowbase = mt * 128 + wm * 64;
    int colbase = nt * 64 + wn * 32;
#pragma unroll
    for (int mi = 0; mi < 4; ++mi)
#pragma unroll
        for (int j = 0; j < 2; ++j)
#pragma unroll
            for (int r = 0; r < 4; ++r) {
                float g = accG[mi][j][r], u = accU[mi][j][r];
                float h = g / (1.f + __expf(-g)) * u;   // silu(g)*u
                int row = rowbase + mi * 16 + quad * 4 + r;   // C/D: col=lane&15, row=quad*4+reg
                int col = colbase + j * 16 + ln;
                Hq[(size_t)row * FQ + col] = f2bf(h);
            }
}

// ---------------- GEMM2 partial: out[tok] += w * (Hq @ WdTq^T) ----------------
// grid (D_/64=32, 65), 256 thr = 4 waves (2x2), per-wave 64x32. BK=64, same swizzle.
__global__ __launch_bounds__(256, 3) void k_gemm2(
    const u16* __restrict__ Hq, const u16* __restrict__ WdT,
    const int* __restrict__ counts, const int* __restrict__ tmap,
    const float* __restrict__ wrow, float* __restrict__ out)
{
    int nt = blockIdx.x, mt = blockIdx.y;
    int count0 = counts[0];
    int level = (mt * 128 < count0) ? 0 : 1;
    const u16* Bd = WdT + (size_t)level * D_ * FQ;

    __shared__ __align__(16) u16 As[8192 + 9728];   // 128x64 + 19KB occupancy pad
    __shared__ __align__(16) u16 Bs[4096];          // 64x64   -> 44KB with stok/sw
    __shared__ int   stok[128];
    __shared__ float sw[128];

    int tid = threadIdx.x, lane = tid & 63, wave = tid >> 6;
    int wm = wave >> 1, wn = wave & 1;
    int quad = lane >> 4, ln = lane & 15;
    int swz = ln & 7;

    if (tid < 128) { stok[tid] = tmap[mt * 128 + tid]; sw[tid] = wrow[mt * 128 + tid]; }

    f32x4 acc[4][2] = {};

    int srow = tid >> 3;
    int sswz = ((tid & 7) ^ (srow & 7)) * 8;
    const u16* gA = Hq + (size_t)(mt * 128 + srow) * FQ + sswz;
    const u16* gB = Bd + (size_t)(nt * 64 + srow) * FQ + sswz;
    u16* dA = As + wave * 512;
    u16* dB = Bs + wave * 512;

    for (int k0 = 0; k0 < FQ; k0 += 64) {
        __syncthreads();
        gl16(gA + k0, dA);
        gl16(gA + (size_t)32 * FQ + k0, dA + 2048);
        gl16(gA + (size_t)64 * FQ + k0, dA + 4096);
        gl16(gA + (size_t)96 * FQ + k0, dA + 6144);
        gl16(gB + k0, dB);
        gl16(gB + (size_t)32 * FQ + k0, dB + 2048);
        __syncthreads();
#pragma unroll
        for (int h = 0; h < 2; ++h) {
            int ks = ((h * 4 + quad) ^ swz) * 8;
            s16x8 a[4], b[2];
#pragma unroll
            for (int i = 0; i < 4; ++i)
                a[i] = *(const s16x8*)(As + (wm * 64 + i * 16 + ln) * 64 + ks);
#pragma unroll
            for (int j = 0; j < 2; ++j)
                b[j] = *(const s16x8*)(Bs + (wn * 32 + j * 16 + ln) * 64 + ks);
#pragma unroll
            for (int mi = 0; mi < 4; ++mi)
#pragma unroll
                for (int j = 0; j < 2; ++j)
                    MF(acc[mi][j], a[mi], b[j]);
        }
    }

    int colbase = nt * 64 + wn * 32;
#pragma unroll
    for (int mi = 0; mi < 4; ++mi)
#pragma unroll
        for (int j = 0; j < 2; ++j)
#pragma unroll
            for (int r = 0; r < 4; ++r) {
                int rl = wm * 64 + mi * 16 + quad * 4 + r;
                int tok = stok[rl];
                if (tok < 0) continue;
                int col = colbase + j * 16 + ln;
                out[(size_t)tok * D_ + col] += sw[rl] * acc[mi][j][r];
            }
}

// ---------------- z-loss write ----------------
__global__ void k_zout(const float* zacc, float* out) {
    float s = 0.f;
#pragma unroll
    for (int i = 0; i < 64; i++) s += zacc[i];
    out[(size_t)NTOK * D_] = s;
}

extern "C" void kernel_launch(void* const* d_in, const int* in_sizes, int n_in,
                              void* d_out, int out_size, void* d_ws, size_t ws_size,
                              hipStream_t stream) {
    const float* hs = (const float*)d_in[0];
    const float* rw = (const float*)d_in[1];
    const float* Wg = (const float*)d_in[2];
    const float* Wu = (const float*)d_in[3];
    const float* Wd = (const float*)d_in[4];
    const float* nw = (const float*)d_in[5];
    float* out = (float*)d_out;

    char* ws = (char*)d_ws;
    int*   counts = (int*)(ws + OFF_CNT);
    float* zacc   = (float*)(ws + OFF_ZL);
    int*   tmap   = (int*)(ws + OFF_MAP);
    float* wrow   = (float*)(ws + OFF_WROW);
    float* wtok   = (float*)(ws + OFF_WTOK);
    u16*   Xg     = (u16*)(ws + OFF_XG);
    u16*   Hq     = (u16*)(ws + OFF_HQ);
    u16*   WA     = (u16*)(ws + OFF_WA);   // WgT quarter, then WdT quarter
    u16*   WB     = (u16*)(ws + OFF_WB);   // WuT quarter

    k_init<<<1, 64, 0, stream>>>(counts, zacc);
    k_router<<<NTOK, 256, 0, stream>>>(hs, rw, nw, counts, zacc, tmap, wrow, wtok, Xg);
    k_gap<<<128, 256, 0, stream>>>(counts, tmap, Xg);
    k_outinit<<<NTOK, 256, 0, stream>>>(hs, wtok, out);

    for (int q = 0; q < 4; q++) {
        // Wg, Wu [L][D][F]: transpose col-range [q*FQ, +FQ) -> [L][FQ][D] (fused launch)
        k_transposeGU<<<dim3(FQ / 32, D_ / 32, 2 * L_), 256, 0, stream>>>(Wg, Wu, WA, WB, q * FQ);
        k_gemm1<<<dim3(FQ / 64, RCAP / 128), 256, 0, stream>>>(Xg, WA, WB, counts, Hq);
        // Wd [L][F][D]: transpose row-range [q*FQ, +FQ) -> [L][D][FQ]  (reuses WA)
        k_transpose<<<dim3(D_ / 32, FQ / 32, L_), 256, 0, stream>>>(Wd, WA, F_, D_, q * FQ, 0, FQ, D_);
        k_gemm2<<<dim3(D_ / 64, RCAP / 128), 256, 0, stream>>>(Hq, WA, counts, tmap, wrow, out);
    }
    k_zout<<<1, 1, 0, stream>>>(zacc, out);
}